// Round 1
// 379.526 us; speedup vs baseline: 1.1595x; 1.1595x over previous
//
#include <hip/hip_runtime.h>
#include <hip/hip_bf16.h>
#include <math.h>

#define BB 2
#define SS 1024
#define HH 2048
#define NHD 16
#define NOPE 128
#define ROPED 64
#define VDIM 128
#define QKD 192
#define QLR 1536
#define KVLR 512
#define EPSF 1e-5f
#define NCOMB 2176   // QLR + 576 kv + 64 pad

typedef __bf16 bf16x8 __attribute__((ext_vector_type(8)));
typedef float  f32x4  __attribute__((ext_vector_type(4)));

__device__ __forceinline__ void gload_lds16(const __bf16* g, __bf16* l) {
    __builtin_amdgcn_global_load_lds(
        (const __attribute__((address_space(1))) void*)g,
        (__attribute__((address_space(3))) void*)l, 16, 0, 0);
}

// ---------------------------------------------------------------------------
// Double-buffered counted-vmcnt GEMM core (128x128 tile, BK=64).
//   - LDS: 2 buffers x (A[128][64] + B[128][64]) bf16 = 64 KB.
//   - XOR swizzle on 16B chunks: LDS slot s of row r holds global chunk
//     s ^ (r&7); staging pre-swizzles the *global* source address (linear
//     LDS dest, required by global_load_lds), fragment ds_reads apply the
//     same XOR. 16-lane column reads -> 2-way banks (free).
//   - Pipeline: while tile t computes, tile t+2 is staged into buf[t&1]
//     (safe: barrier (a) after all reads of buf[t&1]); the tile-boundary
//     wait is vmcnt(8) = t+1 complete, t+2 in flight. No vmcnt(0) drain in
//     steady state. Raw s_barrier, NOT __syncthreads (which drains).
//   Requires K % 64 == 0 and K >= 128 (all call sites satisfy this).
// ---------------------------------------------------------------------------
__device__ __forceinline__ void gemm_core_dbuf(
    const __bf16* __restrict__ Ab, const __bf16* __restrict__ Bb,
    int lda, int ldb, int m0, int n0, int K, __bf16* lds, f32x4 acc[4][4])
{
    const int tid = threadIdx.x;
    const int w = tid >> 6, lane = tid & 63, quad = lane >> 4, ln = lane & 15;
    const int wm = (w >> 1) * 64, wn = (w & 1) * 64;
    const int sr = tid >> 3;                       // staging row within 32-group
    const int sw = ((tid & 7) ^ (sr & 7)) << 3;    // pre-swizzled k-chunk (elems)
    const int nt = K >> 6;

    const __bf16* gA = Ab + (size_t)(m0 + sr) * lda + sw;
    const __bf16* gB = Bb + (size_t)(n0 + sr) * ldb + sw;

    // fragment read offsets (elements), swizzled: slot = (ksub*4+quad)^(row&7)
    const int swq0 = ((quad) ^ (ln & 7)) << 3;
    const int swq1 = ((4 + quad) ^ (ln & 7)) << 3;
    const int aoff0 = (wm + ln) * 64 + swq0;
    const int aoff1 = (wm + ln) * 64 + swq1;
    const int boff0 = (wn + ln) * 64 + swq0;
    const int boff1 = (wn + ln) * 64 + swq1;

    auto stage = [&](int buf, int kk) {
        const __bf16* ga = gA + kk;
        const __bf16* gb = gB + kk;
        __bf16* la = lds + buf * 16384 + w * 512;
        __bf16* lb = la + 8192;
#pragma unroll
        for (int i = 0; i < 4; ++i) {
            gload_lds16(ga + (size_t)(i * 32) * lda, la + i * 2048);
            gload_lds16(gb + (size_t)(i * 32) * ldb, lb + i * 2048);
        }
    };

    // prologue: tile0 -> buf0, tile1 -> buf1; wait tile0 (8 of 16 outstanding)
    stage(0, 0);
    stage(1, 64);
    asm volatile("s_waitcnt vmcnt(8)" ::: "memory");
    __builtin_amdgcn_s_barrier();
    __builtin_amdgcn_sched_barrier(0);

    for (int t = 0; t < nt; ++t) {
        const int cur = t & 1;
        const __bf16* bufA = lds + cur * 16384;
        const __bf16* bufB = bufA + 8192;
        bf16x8 af0[4], af1[4], bv0[4], bv1[4];
#pragma unroll
        for (int i = 0; i < 4; ++i) {
            af0[i] = *(const bf16x8*)&bufA[aoff0 + i * 1024];
            af1[i] = *(const bf16x8*)&bufA[aoff1 + i * 1024];
            bv0[i] = *(const bf16x8*)&bufB[boff0 + i * 1024];
            bv1[i] = *(const bf16x8*)&bufB[boff1 + i * 1024];
        }
        __builtin_amdgcn_s_setprio(1);
#pragma unroll
        for (int mi = 0; mi < 4; ++mi)
#pragma unroll
            for (int ni = 0; ni < 4; ++ni)
                acc[mi][ni] = __builtin_amdgcn_mfma_f32_16x16x32_bf16(
                    af0[mi], bv0[ni], acc[mi][ni], 0, 0, 0);
#pragma unroll
        for (int mi = 0; mi < 4; ++mi)
#pragma unroll
            for (int ni = 0; ni < 4; ++ni)
                acc[mi][ni] = __builtin_amdgcn_mfma_f32_16x16x32_bf16(
                    af1[mi], bv1[ni], acc[mi][ni], 0, 0, 0);
        __builtin_amdgcn_s_setprio(0);
        if (t + 1 < nt) {
            __builtin_amdgcn_sched_barrier(0);
            asm volatile("" ::: "memory");
            __builtin_amdgcn_s_barrier();          // (a) all reads of buf[cur] done
            asm volatile("" ::: "memory");
            if (t + 2 < nt) {
                stage(cur, (t + 2) << 6);          // overwrite buf[cur] with t+2
                asm volatile("s_waitcnt vmcnt(8)" ::: "memory");  // t+1 landed
            } else {
                asm volatile("s_waitcnt vmcnt(0)" ::: "memory");  // last tile
            }
            __builtin_amdgcn_s_barrier();          // (b) publish t+1
            __builtin_amdgcn_sched_barrier(0);
        }
    }
}

// ---------------------------------------------------------------------------
// MFMA bf16 GEMM: C[M,N] = A[M,K] @ B[N,K]^T (batched via blockIdx.z)
// ---------------------------------------------------------------------------
template<bool OUT_BF16>
__global__ __launch_bounds__(256, 2) void gemm_mfma(
    const __bf16* __restrict__ A, const __bf16* __restrict__ B, void* __restrict__ Cv,
    int M, int N, int K, int lda, int ldb, int ldc,
    long long sA, long long sB, long long sC)
{
    __shared__ __bf16 lds[32768];
    const __bf16* Ab = A + (long long)blockIdx.z * sA;
    const __bf16* Bb = B + (long long)blockIdx.z * sB;
    const int tid = threadIdx.x;
    const int w = tid >> 6, lane = tid & 63, quad = lane >> 4, ln = lane & 15;
    const int m0 = blockIdx.y * 128, n0 = blockIdx.x * 128;
    const int wm = (w >> 1) * 64, wn = (w & 1) * 64;

    f32x4 acc[4][4];
#pragma unroll
    for (int i = 0; i < 4; ++i)
#pragma unroll
        for (int j = 0; j < 4; ++j) acc[i][j] = (f32x4){0.f, 0.f, 0.f, 0.f};

    gemm_core_dbuf(Ab, Bb, lda, ldb, m0, n0, K, lds, acc);

    if (OUT_BF16) {
        __bf16* Cb = (__bf16*)Cv + (long long)blockIdx.z * sC;
#pragma unroll
        for (int mi = 0; mi < 4; ++mi)
#pragma unroll
            for (int r = 0; r < 4; ++r) {
                size_t row = (size_t)(m0 + wm + mi * 16 + quad * 4 + r);
#pragma unroll
                for (int ni = 0; ni < 4; ++ni)
                    Cb[row * ldc + (n0 + wn + ni * 16 + ln)] = (__bf16)acc[mi][ni][r];
            }
    } else {
        float* Cb = (float*)Cv + (long long)blockIdx.z * sC;
#pragma unroll
        for (int mi = 0; mi < 4; ++mi)
#pragma unroll
            for (int r = 0; r < 4; ++r) {
                size_t row = (size_t)(m0 + wm + mi * 16 + quad * 4 + r);
#pragma unroll
                for (int ni = 0; ni < 4; ++ni)
                    Cb[row * ldc + (n0 + wn + ni * 16 + ln)] = acc[mi][ni][r];
            }
    }
}

// ---------------------------------------------------------------------------
// Causal scores GEMM: Sc[z] = (Qc[z] @ Kc[b]^T) * scale, bf16 out, diagonal
// masked to -1e30. z = b*16+h. Upper tiles (nt>mt) early-exit.
// ---------------------------------------------------------------------------
__global__ __launch_bounds__(256, 2) void gemm_scores(
    const __bf16* __restrict__ Qc, const __bf16* __restrict__ Kc,
    __bf16* __restrict__ Sc)
{
    const int nt = blockIdx.x, mt = blockIdx.y, z = blockIdx.z;
    if (nt > mt) return;
    const int b = z >> 4;
    __shared__ __bf16 lds[32768];
    const __bf16* Ab = Qc + (size_t)z * SS * 576;
    const __bf16* Bb = Kc + (size_t)b * SS * 576;
    __bf16* Cb = Sc + (size_t)z * SS * SS;
    const int tid = threadIdx.x;
    const int w = tid >> 6, lane = tid & 63, quad = lane >> 4, ln = lane & 15;
    const int m0 = mt * 128, n0 = nt * 128;
    const int wm = (w >> 1) * 64, wn = (w & 1) * 64;

    f32x4 acc[4][4];
#pragma unroll
    for (int i = 0; i < 4; ++i)
#pragma unroll
        for (int j = 0; j < 4; ++j) acc[i][j] = (f32x4){0.f, 0.f, 0.f, 0.f};

    gemm_core_dbuf(Ab, Bb, 576, 576, m0, n0, 576, lds, acc);

    const float SCL2 = 0.07216878364870323f * 1.4426950408889634f;  // scale*log2e
#pragma unroll
    for (int mi = 0; mi < 4; ++mi)
#pragma unroll
        for (int r = 0; r < 4; ++r) {
            int row = m0 + wm + mi * 16 + quad * 4 + r;
#pragma unroll
            for (int ni = 0; ni < 4; ++ni) {
                int col = n0 + wn + ni * 16 + ln;
                float v = acc[mi][ni][r] * SCL2;
                if (col > row) v = -1e30f;
                Cb[(size_t)row * SS + col] = (__bf16)v;
            }
        }
}

// ---------------------------------------------------------------------------
// Row softmax (exp2 domain, scores pre-scaled by scale*log2e). One wave per
// row, shfl-only reductions.
// ---------------------------------------------------------------------------
__global__ __launch_bounds__(256) void softmax_kernel(__bf16* __restrict__ Sc)
{
    const int z = blockIdx.y;
    const int w = threadIdx.x >> 6, lane = threadIdx.x & 63;
    const int r = blockIdx.x * 4 + w;
    __bf16* row = Sc + (size_t)z * SS * SS + (size_t)r * SS;
    const int ncols = ((r >> 7) + 1) << 7;
    const int i0 = lane * 8, i1 = i0 + 512;
    const bool a0 = i0 < ncols, a1 = i1 < ncols;
    float v[16];
    float lmax = -1e30f;
    if (a0) {
        bf16x8 c = *(const bf16x8*)(row + i0);
#pragma unroll
        for (int j = 0; j < 8; ++j) { v[j] = (float)c[j]; lmax = fmaxf(lmax, v[j]); }
    }
    if (a1) {
        bf16x8 c = *(const bf16x8*)(row + i1);
#pragma unroll
        for (int j = 0; j < 8; ++j) { v[8 + j] = (float)c[j]; lmax = fmaxf(lmax, v[8 + j]); }
    }
#pragma unroll
    for (int off = 1; off < 64; off <<= 1) lmax = fmaxf(lmax, __shfl_xor(lmax, off));
    float lsum = 0.f;
    if (a0) {
#pragma unroll
        for (int j = 0; j < 8; ++j) { v[j] = __builtin_amdgcn_exp2f(v[j] - lmax); lsum += v[j]; }
    }
    if (a1) {
#pragma unroll
        for (int j = 0; j < 8; ++j) { v[8 + j] = __builtin_amdgcn_exp2f(v[8 + j] - lmax); lsum += v[8 + j]; }
    }
#pragma unroll
    for (int off = 1; off < 64; off <<= 1) lsum += __shfl_xor(lsum, off);
    const float inv = 1.f / lsum;
    if (a0) {
        bf16x8 c;
#pragma unroll
        for (int j = 0; j < 8; ++j) c[j] = (__bf16)(v[j] * inv);
        *(bf16x8*)(row + i0) = c;
    }
    if (a1) {
        bf16x8 c;
#pragma unroll
        for (int j = 0; j < 8; ++j) c[j] = (__bf16)(v[8 + j] * inv);
        *(bf16x8*)(row + i1) = c;
    }
}

// ---------------------------------------------------------------------------
// PV GEMM: ctx[b, m, h*512+n] = P[z] @ V[b]  (B operand = Vt[b][n][k]).
// Causal k-bound: K_eff = (mt+1)*128.
// ---------------------------------------------------------------------------
__global__ __launch_bounds__(256, 2) void gemm_pv(
    const __bf16* __restrict__ Sc, const __bf16* __restrict__ Vt,
    __bf16* __restrict__ ctx)
{
    const int nt = blockIdx.x, mt = blockIdx.y, z = blockIdx.z;
    const int b = z >> 4, h = z & 15;
    const int Keff = (mt + 1) * 128;
    __shared__ __bf16 lds[32768];
    const __bf16* Ab = Sc + (size_t)z * SS * SS;
    const __bf16* Bb = Vt + (size_t)b * 512 * 1024;
    const int tid = threadIdx.x;
    const int w = tid >> 6, lane = tid & 63, quad = lane >> 4, ln = lane & 15;
    const int m0 = mt * 128, n0 = nt * 128;
    const int wm = (w >> 1) * 64, wn = (w & 1) * 64;

    f32x4 acc[4][4];
#pragma unroll
    for (int i = 0; i < 4; ++i)
#pragma unroll
        for (int j = 0; j < 4; ++j) acc[i][j] = (f32x4){0.f, 0.f, 0.f, 0.f};

    gemm_core_dbuf(Ab, Bb, SS, 1024, m0, n0, Keff, lds, acc);

#pragma unroll
    for (int mi = 0; mi < 4; ++mi)
#pragma unroll
        for (int r = 0; r < 4; ++r) {
            int row = m0 + wm + mi * 16 + quad * 4 + r;
            __bf16* op = ctx + (size_t)(b * SS + row) * (NHD * KVLR) + h * KVLR;
#pragma unroll
            for (int ni = 0; ni < 4; ++ni)
                op[n0 + wn + ni * 16 + ln] = (__bf16)acc[mi][ni][r];
        }
}

// ---------------------------------------------------------------------------
// Cast helpers
// ---------------------------------------------------------------------------
__global__ __launch_bounds__(256) void castf2b(const float* __restrict__ in,
                                               __bf16* __restrict__ out, int n)
{
    int i = (blockIdx.x * 256 + threadIdx.x) * 4;
    if (i < n) {
        float4 v = *(const float4*)(in + i);
        out[i] = (__bf16)v.x; out[i + 1] = (__bf16)v.y;
        out[i + 2] = (__bf16)v.z; out[i + 3] = (__bf16)v.w;
    }
}

// combined [w_qa(1536); w_kva(576); pad(64)] x 2048 -> bf16
__global__ __launch_bounds__(256) void cast_comb(const float* __restrict__ wqa,
                                                 const float* __restrict__ wkva,
                                                 __bf16* __restrict__ out)
{
    int idx = (blockIdx.x * 256 + threadIdx.x) * 4;
    int row = idx >> 11, col = idx & 2047;
    const float* src;
    if (row < 1536)      src = wqa + (size_t)row * 2048 + col;
    else if (row < 2112) src = wkva + (size_t)(row - 1536) * 2048 + col;
    else {
        out[idx] = (__bf16)0.f; out[idx + 1] = (__bf16)0.f;
        out[idx + 2] = (__bf16)0.f; out[idx + 3] = (__bf16)0.f;
        return;
    }
    float4 v = *(const float4*)src;
    out[idx] = (__bf16)v.x; out[idx + 1] = (__bf16)v.y;
    out[idx + 2] = (__bf16)v.z; out[idx + 3] = (__bf16)v.w;
}

// batched transpose-cast: in[z][R][C] fp32 -> out[z][C][R] bf16
__global__ __launch_bounds__(256) void transpose_cast(const float* __restrict__ in,
                                                      __bf16* __restrict__ out,
                                                      int R, int C)
{
    __shared__ float t[32][33];
    in  += (size_t)blockIdx.z * R * C;
    out += (size_t)blockIdx.z * R * C;
    int c0 = blockIdx.x * 32, r0 = blockIdx.y * 32;
    int tx = threadIdx.x & 31, ty = threadIdx.x >> 5;
#pragma unroll
    for (int i = 0; i < 4; ++i) {
        int r = ty + i * 8;
        t[r][tx] = in[(size_t)(r0 + r) * C + c0 + tx];
    }
    __syncthreads();
#pragma unroll
    for (int i = 0; i < 4; ++i) {
        int rr = ty + i * 8;
        out[(size_t)(c0 + rr) * R + r0 + tx] = (__bf16)t[tx][rr];
    }
}

// Kc[b][k][f<512] bf16 -> Vt[b][f][k] bf16 (key-contiguous V)
__global__ __launch_bounds__(256) void transpose_kc(const __bf16* __restrict__ Kc,
                                                    __bf16* __restrict__ Vt)
{
    __shared__ __bf16 t[32][33];
    int b = blockIdx.z;
    int k0 = blockIdx.x * 32, f0 = blockIdx.y * 32;
    int tx = threadIdx.x & 31, ty = threadIdx.x >> 5;   // ty 0..7
    const __bf16* src = Kc + (size_t)b * SS * 576;
#pragma unroll
    for (int i = 0; i < 4; ++i)
        t[ty + i * 8][tx] = src[(size_t)(k0 + ty + i * 8) * 576 + f0 + tx];
    __syncthreads();
    __bf16* dst = Vt + (size_t)b * 512 * 1024;
#pragma unroll
    for (int i = 0; i < 4; ++i)
        dst[(size_t)(f0 + ty + i * 8) * 1024 + k0 + tx] = t[tx][ty + i * 8];
}

// ---------------------------------------------------------------------------
// LayerNorm fp32 in (row stride ldx) -> bf16 out (row stride N).
// ---------------------------------------------------------------------------
__global__ __launch_bounds__(256) void ln_kernel(const float* __restrict__ x,
                                                 const float* __restrict__ w,
                                                 __bf16* __restrict__ y, int N, int ldx)
{
    long long row = blockIdx.x;
    const float* xr = x + row * ldx;
    __bf16* yr = y + row * N;
    int tid = threadIdx.x;
    float s = 0.f, ss = 0.f;
    for (int i = tid; i < N; i += 256) { float v = xr[i]; s += v; ss += v * v; }
#pragma unroll
    for (int off = 32; off > 0; off >>= 1) { s += __shfl_down(s, off); ss += __shfl_down(ss, off); }
    __shared__ float rs[4], rss[4];
    __shared__ float smean, sinv;
    int wave = tid >> 6, lane = tid & 63;
    if (lane == 0) { rs[wave] = s; rss[wave] = ss; }
    __syncthreads();
    if (tid == 0) {
        float S = rs[0] + rs[1] + rs[2] + rs[3];
        float Q = rss[0] + rss[1] + rss[2] + rss[3];
        float mean = S / N;
        float var = Q / N - mean * mean;
        smean = mean; sinv = rsqrtf(var + EPSF);
    }
    __syncthreads();
    float mean = smean, inv = sinv;
    for (int i = tid; i < N; i += 256) yr[i] = (__bf16)((xr[i] - mean) * inv * w[i]);
}

// ---------------------------------------------------------------------------
// Per-token prep: Kc[row] = bf16(concat(LN(kva[:512])*w, rope(kva[512:576])))
// kva row stride ld; rope q_pe in place inside bf16 q.
// ---------------------------------------------------------------------------
__global__ __launch_bounds__(256) void prep_kernel(
    const float* __restrict__ kva, int ld, const float* __restrict__ kvw,
    const float* __restrict__ cosb, const float* __restrict__ sinb,
    __bf16* __restrict__ Kc, __bf16* __restrict__ q)
{
    long long row = blockIdx.x;
    const float* kr = kva + row * ld;
    const float* cr = cosb + row * ROPED;
    const float* sr = sinb + row * ROPED;
    int tid = threadIdx.x;
    float v0 = kr[tid], v1 = kr[tid + 256];
    float s = v0 + v1, ss = v0 * v0 + v1 * v1;
#pragma unroll
    for (int off = 32; off > 0; off >>= 1) { s += __shfl_down(s, off); ss += __shfl_down(ss, off); }
    __shared__ float rs[4], rss[4];
    __shared__ float smean, sinv;
    int wave = tid >> 6, lane = tid & 63;
    if (lane == 0) { rs[wave] = s; rss[wave] = ss; }
    __syncthreads();
    if (tid == 0) {
        float S = rs[0] + rs[1] + rs[2] + rs[3];
        float Q = rss[0] + rss[1] + rss[2] + rss[3];
        float mean = S / KVLR;
        float var = Q / KVLR - mean * mean;
        smean = mean; sinv = rsqrtf(var + EPSF);
    }
    __syncthreads();
    float mean = smean, inv = sinv;
    __bf16* kc = Kc + row * 576;
    kc[tid]       = (__bf16)((v0 - mean) * inv * kvw[tid]);
    kc[tid + 256] = (__bf16)((v1 - mean) * inv * kvw[tid + 256]);
    if (tid < 32) {
        float x1 = kr[KVLR + tid], x2 = kr[KVLR + 32 + tid];
        kc[512 + tid]      = (__bf16)(x1 * cr[tid] - x2 * sr[tid]);
        kc[512 + 32 + tid] = (__bf16)(x2 * cr[32 + tid] + x1 * sr[32 + tid]);
    }
    __bf16* qr = q + row * (NHD * QKD);
#pragma unroll
    for (int j = 0; j < 2; ++j) {
        int idx = tid + j * 256;
        int h = idx >> 5, p = idx & 31;
        __bf16* base = qr + h * QKD + NOPE;
        float x1 = (float)base[p], x2 = (float)base[32 + p];
        base[p]      = (__bf16)(x1 * cr[p] - x2 * sr[p]);
        base[32 + p] = (__bf16)(x2 * cr[32 + p] + x1 * sr[32 + p]);
    }
}

// ---------------------------------------------------------------------------
// Qc bf16 [B][NH][S][576] = concat(qlat_b, roped q_pe bf16)
// ---------------------------------------------------------------------------
__global__ __launch_bounds__(256) void qcast_kernel(
    const __bf16* __restrict__ qlat, const __bf16* __restrict__ qb,
    __bf16* __restrict__ Qc)
{
    long long row = blockIdx.x;           // b*S + s
    int b = (int)(row >> 10), s = (int)(row & 1023);
    int tid = threadIdx.x;
    for (int i = tid; i < NHD * 576; i += 256) {
        int h = i / 576, c = i - h * 576;
        __bf16 v = (c < 512) ? qlat[row * (NHD * 512) + h * 512 + c]
                             : qb[row * (NHD * QKD) + h * QKD + NOPE + (c - 512)];
        Qc[(((size_t)(b * NHD + h)) * SS + s) * 576 + c] = v;
    }
}

// ---------------------------------------------------------------------------
extern "C" void kernel_launch(void* const* d_in, const int* in_sizes, int n_in,
                              void* d_out, int out_size, void* d_ws, size_t ws_size,
                              hipStream_t stream)
{
    const float* hidden    = (const float*)d_in[0];
    const float* cosb      = (const float*)d_in[1];
    const float* sinb      = (const float*)d_in[2];
    const float* w_qa      = (const float*)d_in[3];
    const float* q_a_ln_w  = (const float*)d_in[4];
    const float* w_qb      = (const float*)d_in[5];
    const float* w_kva     = (const float*)d_in[6];
    const float* kv_a_ln_w = (const float*)d_in[7];
    const float* W_UK_T    = (const float*)d_in[8];
    const float* W_UV      = (const float*)d_in[9];
    const float* w_o       = (const float*)d_in[10];
    float* out = (float*)d_out;

    const int M = BB * SS;  // 2048
    // ---- HEAD region: transient buffers, later aliased by Sc (67.1 MB) ----
    float*  qakva = (float*)d_ws;
    __bf16* Xb    = (__bf16*)(qakva + (size_t)M * NCOMB);
    __bf16* qab   = Xb    + (size_t)M * HH;
    __bf16* qb    = qab   + (size_t)M * QLR;
    __bf16* qlatb = qb    + (size_t)M * NHD * QKD;
    __bf16* Sc    = (__bf16*)d_ws;                    // aliases head after qcast
    // ---- TAIL region: persistent ----
    __bf16* Kc    = qlatb + (size_t)M * NHD * KVLR;   // M*576
    __bf16* Qc    = Kc    + (size_t)M * 576;          // M*9216
    __bf16* Vt    = Qc    + (size_t)M * NHD * 576;    // 2*512*1024
    __bf16* ctxb  = Vt    + (size_t)BB * 512 * SS;    // M*8192
    __bf16* ohb   = ctxb  + (size_t)M * NHD * KVLR;   // M*2048
    __bf16* w_cmb = ohb   + (size_t)M * HH;           // 2176*2048
    __bf16* w_qbb = w_cmb + (size_t)NCOMB * HH;       // 3072*1536
    __bf16* Wkb   = w_qbb + (size_t)NHD * QKD * QLR;  // 16*512*128
    __bf16* Wvb   = Wkb   + (size_t)NHD * KVLR * NOPE;// 16*128*512
    __bf16* w_ob  = Wvb   + (size_t)NHD * VDIM * KVLR;// 2048*2048

    dim3 blk(256);

    // --- casts ---
    castf2b<<<dim3((M * HH) / 1024), blk, 0, stream>>>(hidden, Xb, M * HH);
    cast_comb<<<dim3((NCOMB * HH) / 1024), blk, 0, stream>>>(w_qa, w_kva, w_cmb);
    castf2b<<<dim3((NHD * QKD * QLR) / 1024), blk, 0, stream>>>(w_qb, w_qbb, NHD * QKD * QLR);
    castf2b<<<dim3((HH * HH) / 1024), blk, 0, stream>>>(w_o, w_ob, HH * HH);
    transpose_cast<<<dim3(KVLR / 32, NOPE / 32, NHD), blk, 0, stream>>>(W_UK_T, Wkb, NOPE, KVLR);
    transpose_cast<<<dim3(VDIM / 32, KVLR / 32, NHD), blk, 0, stream>>>(W_UV, Wvb, KVLR, VDIM);

    // 1+4 fused: qakva = Xb @ [w_qa; w_kva]^T   (2048 x 2176 x 2048)
    gemm_mfma<false><<<dim3(NCOMB / 128, M / 128, 1), blk, 0, stream>>>(
        Xb, w_cmb, qakva, M, NCOMB, HH, HH, HH, NCOMB, 0, 0, 0);
    // 2. qab = bf16(LN(qakva[:, :1536]))
    ln_kernel<<<dim3(M), blk, 0, stream>>>(qakva, q_a_ln_w, qab, QLR, NCOMB);
    // 3. qb = qab @ w_qb^T (bf16)              (2048 x 3072 x 1536)
    gemm_mfma<true><<<dim3(NHD * QKD / 128, M / 128, 1), blk, 0, stream>>>(
        qab, w_qbb, qb, M, NHD * QKD, QLR, QLR, QLR, NHD * QKD, 0, 0, 0);
    // 5. Kc = [LN(kv_c), rope(k_pe)] bf16; rope q_pe in place (bf16)
    prep_kernel<<<dim3(M), blk, 0, stream>>>(qakva + QLR, NCOMB, kv_a_ln_w,
                                             cosb, sinb, Kc, qb);
    // 5b. Vt = transpose(Kc[:, :512])
    transpose_kc<<<dim3(SS / 32, 512 / 32, BB), blk, 0, stream>>>(Kc, Vt);
    // 6. qlatb[h] = q_nope[h] @ Wkb[h]^T       (16 x [2048 x 512 x 128])
    gemm_mfma<true><<<dim3(KVLR / 128, M / 128, NHD), blk, 0, stream>>>(
        qb, Wkb, qlatb, M, KVLR, NOPE,
        NHD * QKD, NOPE, NHD * KVLR,
        (long long)QKD, (long long)KVLR * NOPE, (long long)KVLR);
    // 7. Qc = concat(qlatb, roped q_pe), layout [B,NH,S,576]
    qcast_kernel<<<dim3(M), blk, 0, stream>>>(qlatb, qb, Qc);
    // 8a. Sc = causal scores (Qc @ Kc^T)*scale  [bf16, head region now dead]
    gemm_scores<<<dim3(8, 8, 32), blk, 0, stream>>>(Qc, Kc, Sc);
    // 8b. row softmax in place
    softmax_kernel<<<dim3(SS / 4, 32), blk, 0, stream>>>(Sc);
    // 8c. ctx = P @ V (causal k-bound)
    gemm_pv<<<dim3(4, 8, 32), blk, 0, stream>>>(Sc, Vt, ctxb);
    // 9. ohb[h] = ctx[h] @ Wvb[h]^T            (16 x [2048 x 128 x 512])
    gemm_mfma<true><<<dim3(VDIM / 128, M / 128, NHD), blk, 0, stream>>>(
        ctxb, Wvb, ohb, M, VDIM, KVLR,
        NHD * KVLR, KVLR, NHD * VDIM,
        (long long)KVLR, (long long)VDIM * KVLR, (long long)VDIM);
    // 10. out = ohb @ w_o^T (fp32)             (2048 x 2048 x 2048)
    gemm_mfma<false><<<dim3(HH / 128, M / 128, 1), blk, 0, stream>>>(
        ohb, w_ob, out, M, HH, NHD * VDIM, NHD * VDIM, NHD * VDIM, HH, 0, 0, 0);
}

// Round 2
// 375.076 us; speedup vs baseline: 1.1733x; 1.0119x over previous
//
#include <hip/hip_runtime.h>
#include <hip/hip_bf16.h>
#include <math.h>

#define BB 2
#define SS 1024
#define HH 2048
#define NHD 16
#define NOPE 128
#define ROPED 64
#define VDIM 128
#define QKD 192
#define QLR 1536
#define KVLR 512
#define EPSF 1e-5f
#define NCOMB 2176   // QLR + 576 kv + 64 pad

typedef __bf16 bf16x8 __attribute__((ext_vector_type(8)));
typedef float  f32x4  __attribute__((ext_vector_type(4)));

__device__ __forceinline__ void gload_lds16(const __bf16* g, __bf16* l) {
    __builtin_amdgcn_global_load_lds(
        (const __attribute__((address_space(1))) void*)g,
        (__attribute__((address_space(3))) void*)l, 16, 0, 0);
}

// ---------------------------------------------------------------------------
// Double-buffered counted-vmcnt GEMM core (128x128 tile), templated on BK.
//   BK=64: 64 KB LDS, 2 blocks/CU  (for small grids / big-K dense GEMMs)
//   BK=32: 32 KB LDS, 5 blocks/CU  (for large grids: scores/pv/qlat/wv)
//   - XOR swizzle on 16B chunks; involution applied to pre-swizzled GLOBAL
//     source (LDS dest stays linear, required by global_load_lds) and to the
//     ds_read addresses.  BK=64: chunk^=(row&7) (R1: measured 0 conflicts).
//     BK=32: chunk^=((row>>1)&3) -> rows r,r+8 alias = 2-way = free.
//   - Pipeline: stage t+2 while computing t; tile-boundary wait is
//     vmcnt(loads-per-stage) so t+2 stays in flight. Raw s_barrier only.
//   Requires K % BK == 0, K >= 2*BK.
// ---------------------------------------------------------------------------
template<int BK>
__device__ __forceinline__ void gemm_core_dbuf(
    const __bf16* __restrict__ Ab, const __bf16* __restrict__ Bb,
    int lda, int ldb, int m0, int n0, int K, __bf16* lds, f32x4 acc[4][4])
{
    constexpr int CH    = BK / 8;      // 16B chunks per row
    constexpr int LPT   = CH / 2;      // stage instrs per thread per operand
    constexpr int BUFE  = 256 * BK;    // elems per buffer (A+B)
    constexpr int BOFF  = 128 * BK;    // B offset inside buffer
    constexpr int RSTEP = 2048 / BK;   // rows per stage-instr step
    const int tid = threadIdx.x;
    const int w = tid >> 6, lane = tid & 63, quad = lane >> 4, ln = lane & 15;
    const int wm = (w >> 1) * 64, wn = (w & 1) * 64;
    const int nt = K / BK;

    // staging: thread covers chunk (row=sr(+i*RSTEP), phys-chunk=spc);
    // global source uses logical chunk sc = spc ^ swz(row) (swz invariant
    // under row += RSTEP for both BK variants).
    const int sr  = tid / CH;
    const int spc = tid % CH;
    const int sc  = (BK == 64) ? (spc ^ (sr & 7)) : (spc ^ ((sr >> 1) & 3));
    const __bf16* gA = Ab + (size_t)(m0 + sr) * lda + sc * 8;
    const __bf16* gB = Bb + (size_t)(n0 + sr) * ldb + sc * 8;

    // fragment-read swizzle terms (invariant under row += 16, i.e. mi)
    const int swm = (BK == 64) ? ((wm + ln) & 7) : (((wm + ln) >> 1) & 3);
    const int swn = (BK == 64) ? ((wn + ln) & 7) : (((wn + ln) >> 1) & 3);

    auto stage = [&](int buf, int kk) {
        __bf16* la = lds + buf * BUFE + w * 512;
        __bf16* lb = la + BOFF;
        const __bf16* ga = gA + kk;
        const __bf16* gb = gB + kk;
#pragma unroll
        for (int i = 0; i < LPT; ++i) {
            gload_lds16(ga + (size_t)(i * RSTEP) * lda, la + i * 2048);
            gload_lds16(gb + (size_t)(i * RSTEP) * ldb, lb + i * 2048);
        }
    };
    auto wait_stage = [&]() {
        if constexpr (BK == 64) asm volatile("s_waitcnt vmcnt(8)" ::: "memory");
        else                    asm volatile("s_waitcnt vmcnt(4)" ::: "memory");
    };

    // prologue: tile0 -> buf0, tile1 -> buf1; wait tile0 only
    stage(0, 0);
    stage(1, BK);
    wait_stage();
    __builtin_amdgcn_s_barrier();
    __builtin_amdgcn_sched_barrier(0);

    for (int t = 0; t < nt; ++t) {
        const int cur = t & 1;
        const __bf16* bufA = lds + cur * BUFE;
        const __bf16* bufB = bufA + BOFF;
        bf16x8 af[BK / 32][4], bv[BK / 32][4];
#pragma unroll
        for (int ks = 0; ks < BK / 32; ++ks)
#pragma unroll
            for (int i = 0; i < 4; ++i) {
                af[ks][i] = *(const bf16x8*)
                    &bufA[(wm + ln) * BK + i * 16 * BK + (((ks * 4 + quad) ^ swm) << 3)];
                bv[ks][i] = *(const bf16x8*)
                    &bufB[(wn + ln) * BK + i * 16 * BK + (((ks * 4 + quad) ^ swn) << 3)];
            }
        __builtin_amdgcn_s_setprio(1);
#pragma unroll
        for (int ks = 0; ks < BK / 32; ++ks)
#pragma unroll
            for (int mi = 0; mi < 4; ++mi)
#pragma unroll
                for (int ni = 0; ni < 4; ++ni)
                    acc[mi][ni] = __builtin_amdgcn_mfma_f32_16x16x32_bf16(
                        af[ks][mi], bv[ks][ni], acc[mi][ni], 0, 0, 0);
        __builtin_amdgcn_s_setprio(0);
        if (t + 1 < nt) {
            __builtin_amdgcn_sched_barrier(0);
            asm volatile("" ::: "memory");
            __builtin_amdgcn_s_barrier();          // (a) reads of buf[cur] done
            asm volatile("" ::: "memory");
            if (t + 2 < nt) {
                stage(cur, (t + 2) * BK);          // overwrite buf[cur] w/ t+2
                wait_stage();                      // t+1 landed, t+2 in flight
            } else {
                asm volatile("s_waitcnt vmcnt(0)" ::: "memory");
            }
            __builtin_amdgcn_s_barrier();          // (b) publish t+1
            __builtin_amdgcn_sched_barrier(0);
        }
    }
}

// ---------------------------------------------------------------------------
// MFMA bf16 GEMM: C[M,N] = A[M,K] @ B[N,K]^T (batched via blockIdx.z)
// ---------------------------------------------------------------------------
template<bool OUT_BF16, int BK, int MINW>
__global__ __launch_bounds__(256, MINW) void gemm_mfma(
    const __bf16* __restrict__ A, const __bf16* __restrict__ B, void* __restrict__ Cv,
    int M, int N, int K, int lda, int ldb, int ldc,
    long long sA, long long sB, long long sC)
{
    __shared__ __bf16 lds[512 * BK];
    const __bf16* Ab = A + (long long)blockIdx.z * sA;
    const __bf16* Bb = B + (long long)blockIdx.z * sB;
    const int tid = threadIdx.x;
    const int w = tid >> 6, lane = tid & 63, quad = lane >> 4, ln = lane & 15;
    const int m0 = blockIdx.y * 128, n0 = blockIdx.x * 128;
    const int wm = (w >> 1) * 64, wn = (w & 1) * 64;

    f32x4 acc[4][4];
#pragma unroll
    for (int i = 0; i < 4; ++i)
#pragma unroll
        for (int j = 0; j < 4; ++j) acc[i][j] = (f32x4){0.f, 0.f, 0.f, 0.f};

    gemm_core_dbuf<BK>(Ab, Bb, lda, ldb, m0, n0, K, lds, acc);

    if (OUT_BF16) {
        __bf16* Cb = (__bf16*)Cv + (long long)blockIdx.z * sC;
#pragma unroll
        for (int mi = 0; mi < 4; ++mi)
#pragma unroll
            for (int r = 0; r < 4; ++r) {
                size_t row = (size_t)(m0 + wm + mi * 16 + quad * 4 + r);
#pragma unroll
                for (int ni = 0; ni < 4; ++ni)
                    Cb[row * ldc + (n0 + wn + ni * 16 + ln)] = (__bf16)acc[mi][ni][r];
            }
    } else {
        float* Cb = (float*)Cv + (long long)blockIdx.z * sC;
#pragma unroll
        for (int mi = 0; mi < 4; ++mi)
#pragma unroll
            for (int r = 0; r < 4; ++r) {
                size_t row = (size_t)(m0 + wm + mi * 16 + quad * 4 + r);
#pragma unroll
                for (int ni = 0; ni < 4; ++ni)
                    Cb[row * ldc + (n0 + wn + ni * 16 + ln)] = acc[mi][ni][r];
            }
    }
}

// ---------------------------------------------------------------------------
// qlat GEMM with fused Qc scatter: Qc[b][h][s][0..512) = q_nope[h] @ Wk[h]^T
// z = h. A = qb (nope cols), B = Wkb[h]. Writes directly into Qc layout.
// ---------------------------------------------------------------------------
__global__ __launch_bounds__(256, 4) void gemm_qlat(
    const __bf16* __restrict__ qb, const __bf16* __restrict__ Wkb,
    __bf16* __restrict__ Qc)
{
    __shared__ __bf16 lds[512 * 32];
    const int h = blockIdx.z;
    const __bf16* Ab = qb + (size_t)h * QKD;
    const __bf16* Bb = Wkb + (size_t)h * KVLR * NOPE;
    const int tid = threadIdx.x;
    const int w = tid >> 6, lane = tid & 63, quad = lane >> 4, ln = lane & 15;
    const int m0 = blockIdx.y * 128, n0 = blockIdx.x * 128;
    const int wm = (w >> 1) * 64, wn = (w & 1) * 64;

    f32x4 acc[4][4];
#pragma unroll
    for (int i = 0; i < 4; ++i)
#pragma unroll
        for (int j = 0; j < 4; ++j) acc[i][j] = (f32x4){0.f, 0.f, 0.f, 0.f};

    gemm_core_dbuf<32>(Ab, Bb, NHD * QKD, NOPE, m0, n0, NOPE, lds, acc);

#pragma unroll
    for (int mi = 0; mi < 4; ++mi)
#pragma unroll
        for (int r = 0; r < 4; ++r) {
            int row = m0 + wm + mi * 16 + quad * 4 + r;   // b*S + s
            int bb = row >> 10, s = row & 1023;
            __bf16* dst = Qc + ((size_t)(bb * NHD + h) * SS + s) * 576;
#pragma unroll
            for (int ni = 0; ni < 4; ++ni)
                dst[n0 + wn + ni * 16 + ln] = (__bf16)acc[mi][ni][r];
        }
}

// ---------------------------------------------------------------------------
// Causal scores GEMM: Sc[z] = (Qc[z] @ Kc[b]^T) * scale, bf16 out, diagonal
// masked to -1e30. z = b*16+h. Upper tiles (nt>mt) early-exit.
// ---------------------------------------------------------------------------
__global__ __launch_bounds__(256, 4) void gemm_scores(
    const __bf16* __restrict__ Qc, const __bf16* __restrict__ Kc,
    __bf16* __restrict__ Sc)
{
    const int nt = blockIdx.x, mt = blockIdx.y, z = blockIdx.z;
    if (nt > mt) return;
    const int b = z >> 4;
    __shared__ __bf16 lds[512 * 32];
    const __bf16* Ab = Qc + (size_t)z * SS * 576;
    const __bf16* Bb = Kc + (size_t)b * SS * 576;
    __bf16* Cb = Sc + (size_t)z * SS * SS;
    const int tid = threadIdx.x;
    const int w = tid >> 6, lane = tid & 63, quad = lane >> 4, ln = lane & 15;
    const int m0 = mt * 128, n0 = nt * 128;
    const int wm = (w >> 1) * 64, wn = (w & 1) * 64;

    f32x4 acc[4][4];
#pragma unroll
    for (int i = 0; i < 4; ++i)
#pragma unroll
        for (int j = 0; j < 4; ++j) acc[i][j] = (f32x4){0.f, 0.f, 0.f, 0.f};

    gemm_core_dbuf<32>(Ab, Bb, 576, 576, m0, n0, 576, lds, acc);

    const float SCL2 = 0.07216878364870323f * 1.4426950408889634f;  // scale*log2e
#pragma unroll
    for (int mi = 0; mi < 4; ++mi)
#pragma unroll
        for (int r = 0; r < 4; ++r) {
            int row = m0 + wm + mi * 16 + quad * 4 + r;
#pragma unroll
            for (int ni = 0; ni < 4; ++ni) {
                int col = n0 + wn + ni * 16 + ln;
                float v = acc[mi][ni][r] * SCL2;
                if (col > row) v = -1e30f;
                Cb[(size_t)row * SS + col] = (__bf16)v;
            }
        }
}

// ---------------------------------------------------------------------------
// Row softmax (exp2 domain, scores pre-scaled by scale*log2e). One wave per
// row, shfl-only reductions.
// ---------------------------------------------------------------------------
__global__ __launch_bounds__(256) void softmax_kernel(__bf16* __restrict__ Sc)
{
    const int z = blockIdx.y;
    const int w = threadIdx.x >> 6, lane = threadIdx.x & 63;
    const int r = blockIdx.x * 4 + w;
    __bf16* row = Sc + (size_t)z * SS * SS + (size_t)r * SS;
    const int ncols = ((r >> 7) + 1) << 7;
    const int i0 = lane * 8, i1 = i0 + 512;
    const bool a0 = i0 < ncols, a1 = i1 < ncols;
    float v[16];
    float lmax = -1e30f;
    if (a0) {
        bf16x8 c = *(const bf16x8*)(row + i0);
#pragma unroll
        for (int j = 0; j < 8; ++j) { v[j] = (float)c[j]; lmax = fmaxf(lmax, v[j]); }
    }
    if (a1) {
        bf16x8 c = *(const bf16x8*)(row + i1);
#pragma unroll
        for (int j = 0; j < 8; ++j) { v[8 + j] = (float)c[j]; lmax = fmaxf(lmax, v[8 + j]); }
    }
#pragma unroll
    for (int off = 1; off < 64; off <<= 1) lmax = fmaxf(lmax, __shfl_xor(lmax, off));
    float lsum = 0.f;
    if (a0) {
#pragma unroll
        for (int j = 0; j < 8; ++j) { v[j] = __builtin_amdgcn_exp2f(v[j] - lmax); lsum += v[j]; }
    }
    if (a1) {
#pragma unroll
        for (int j = 0; j < 8; ++j) { v[8 + j] = __builtin_amdgcn_exp2f(v[8 + j] - lmax); lsum += v[8 + j]; }
    }
#pragma unroll
    for (int off = 1; off < 64; off <<= 1) lsum += __shfl_xor(lsum, off);
    const float inv = 1.f / lsum;
    if (a0) {
        bf16x8 c;
#pragma unroll
        for (int j = 0; j < 8; ++j) c[j] = (__bf16)(v[j] * inv);
        *(bf16x8*)(row + i0) = c;
    }
    if (a1) {
        bf16x8 c;
#pragma unroll
        for (int j = 0; j < 8; ++j) c[j] = (__bf16)(v[8 + j] * inv);
        *(bf16x8*)(row + i1) = c;
    }
}

// ---------------------------------------------------------------------------
// PV GEMM: ctx[b, m, h*512+n] = P[z] @ V[b]  (B operand = Vt[b][n][k]).
// Causal k-bound: K_eff = (mt+1)*128.
// ---------------------------------------------------------------------------
__global__ __launch_bounds__(256, 4) void gemm_pv(
    const __bf16* __restrict__ Sc, const __bf16* __restrict__ Vt,
    __bf16* __restrict__ ctx)
{
    const int nt = blockIdx.x, mt = blockIdx.y, z = blockIdx.z;
    const int b = z >> 4, h = z & 15;
    const int Keff = (mt + 1) * 128;
    __shared__ __bf16 lds[512 * 32];
    const __bf16* Ab = Sc + (size_t)z * SS * SS;
    const __bf16* Bb = Vt + (size_t)b * 512 * 1024;
    const int tid = threadIdx.x;
    const int w = tid >> 6, lane = tid & 63, quad = lane >> 4, ln = lane & 15;
    const int m0 = mt * 128, n0 = nt * 128;
    const int wm = (w >> 1) * 64, wn = (w & 1) * 64;

    f32x4 acc[4][4];
#pragma unroll
    for (int i = 0; i < 4; ++i)
#pragma unroll
        for (int j = 0; j < 4; ++j) acc[i][j] = (f32x4){0.f, 0.f, 0.f, 0.f};

    gemm_core_dbuf<32>(Ab, Bb, SS, 1024, m0, n0, Keff, lds, acc);

#pragma unroll
    for (int mi = 0; mi < 4; ++mi)
#pragma unroll
        for (int r = 0; r < 4; ++r) {
            int row = m0 + wm + mi * 16 + quad * 4 + r;
            __bf16* op = ctx + (size_t)(b * SS + row) * (NHD * KVLR) + h * KVLR;
#pragma unroll
            for (int ni = 0; ni < 4; ++ni)
                op[n0 + wn + ni * 16 + ln] = (__bf16)acc[mi][ni][r];
        }
}

// ---------------------------------------------------------------------------
// Cast helpers
// ---------------------------------------------------------------------------
__global__ __launch_bounds__(256) void castf2b(const float* __restrict__ in,
                                               __bf16* __restrict__ out, int n)
{
    int i = (blockIdx.x * 256 + threadIdx.x) * 4;
    if (i < n) {
        float4 v = *(const float4*)(in + i);
        out[i] = (__bf16)v.x; out[i + 1] = (__bf16)v.y;
        out[i + 2] = (__bf16)v.z; out[i + 3] = (__bf16)v.w;
    }
}

// combined [w_qa(1536); w_kva(576); pad(64)] x 2048 -> bf16
__global__ __launch_bounds__(256) void cast_comb(const float* __restrict__ wqa,
                                                 const float* __restrict__ wkva,
                                                 __bf16* __restrict__ out)
{
    int idx = (blockIdx.x * 256 + threadIdx.x) * 4;
    int row = idx >> 11, col = idx & 2047;
    const float* src;
    if (row < 1536)      src = wqa + (size_t)row * 2048 + col;
    else if (row < 2112) src = wkva + (size_t)(row - 1536) * 2048 + col;
    else {
        out[idx] = (__bf16)0.f; out[idx + 1] = (__bf16)0.f;
        out[idx + 2] = (__bf16)0.f; out[idx + 3] = (__bf16)0.f;
        return;
    }
    float4 v = *(const float4*)src;
    out[idx] = (__bf16)v.x; out[idx + 1] = (__bf16)v.y;
    out[idx + 2] = (__bf16)v.z; out[idx + 3] = (__bf16)v.w;
}

// batched transpose-cast: in[z][R][C] fp32 -> out[z][C][R] bf16
__global__ __launch_bounds__(256) void transpose_cast(const float* __restrict__ in,
                                                      __bf16* __restrict__ out,
                                                      int R, int C)
{
    __shared__ float t[32][33];
    in  += (size_t)blockIdx.z * R * C;
    out += (size_t)blockIdx.z * R * C;
    int c0 = blockIdx.x * 32, r0 = blockIdx.y * 32;
    int tx = threadIdx.x & 31, ty = threadIdx.x >> 5;
#pragma unroll
    for (int i = 0; i < 4; ++i) {
        int r = ty + i * 8;
        t[r][tx] = in[(size_t)(r0 + r) * C + c0 + tx];
    }
    __syncthreads();
#pragma unroll
    for (int i = 0; i < 4; ++i) {
        int rr = ty + i * 8;
        out[(size_t)(c0 + rr) * R + r0 + tx] = (__bf16)t[tx][rr];
    }
}

// Kc[b][k][f<512] bf16 -> Vt[b][f][k] bf16 (key-contiguous V)
__global__ __launch_bounds__(256) void transpose_kc(const __bf16* __restrict__ Kc,
                                                    __bf16* __restrict__ Vt)
{
    __shared__ __bf16 t[32][33];
    int b = blockIdx.z;
    int k0 = blockIdx.x * 32, f0 = blockIdx.y * 32;
    int tx = threadIdx.x & 31, ty = threadIdx.x >> 5;   // ty 0..7
    const __bf16* src = Kc + (size_t)b * SS * 576;
#pragma unroll
    for (int i = 0; i < 4; ++i)
        t[ty + i * 8][tx] = src[(size_t)(k0 + ty + i * 8) * 576 + f0 + tx];
    __syncthreads();
    __bf16* dst = Vt + (size_t)b * 512 * 1024;
#pragma unroll
    for (int i = 0; i < 4; ++i)
        dst[(size_t)(f0 + ty + i * 8) * 1024 + k0 + tx] = t[tx][ty + i * 8];
}

// ---------------------------------------------------------------------------
// LayerNorm fp32 in (row stride ldx) -> bf16 out (row stride N).
// ---------------------------------------------------------------------------
__global__ __launch_bounds__(256) void ln_kernel(const float* __restrict__ x,
                                                 const float* __restrict__ w,
                                                 __bf16* __restrict__ y, int N, int ldx)
{
    long long row = blockIdx.x;
    const float* xr = x + row * ldx;
    __bf16* yr = y + row * N;
    int tid = threadIdx.x;
    float s = 0.f, ss = 0.f;
    for (int i = tid; i < N; i += 256) { float v = xr[i]; s += v; ss += v * v; }
#pragma unroll
    for (int off = 32; off > 0; off >>= 1) { s += __shfl_down(s, off); ss += __shfl_down(ss, off); }
    __shared__ float rs[4], rss[4];
    __shared__ float smean, sinv;
    int wave = tid >> 6, lane = tid & 63;
    if (lane == 0) { rs[wave] = s; rss[wave] = ss; }
    __syncthreads();
    if (tid == 0) {
        float S = rs[0] + rs[1] + rs[2] + rs[3];
        float Q = rss[0] + rss[1] + rss[2] + rss[3];
        float mean = S / N;
        float var = Q / N - mean * mean;
        smean = mean; sinv = rsqrtf(var + EPSF);
    }
    __syncthreads();
    float mean = smean, inv = sinv;
    for (int i = tid; i < N; i += 256) yr[i] = (__bf16)((xr[i] - mean) * inv * w[i]);
}

// ---------------------------------------------------------------------------
// Per-token prep: Kc[row] = bf16(concat(LN(kva[:512])*w, rope(kva[512:576])))
// kva row stride ld; roped q_pe written straight into Qc cols [512,576).
// ---------------------------------------------------------------------------
__global__ __launch_bounds__(256) void prep_kernel(
    const float* __restrict__ kva, int ld, const float* __restrict__ kvw,
    const float* __restrict__ cosb, const float* __restrict__ sinb,
    __bf16* __restrict__ Kc, const __bf16* __restrict__ q,
    __bf16* __restrict__ Qc)
{
    long long row = blockIdx.x;
    const float* kr = kva + row * ld;
    const float* cr = cosb + row * ROPED;
    const float* sr = sinb + row * ROPED;
    int tid = threadIdx.x;
    float v0 = kr[tid], v1 = kr[tid + 256];
    float s = v0 + v1, ss = v0 * v0 + v1 * v1;
#pragma unroll
    for (int off = 32; off > 0; off >>= 1) { s += __shfl_down(s, off); ss += __shfl_down(ss, off); }
    __shared__ float rs[4], rss[4];
    __shared__ float smean, sinv;
    int wave = tid >> 6, lane = tid & 63;
    if (lane == 0) { rs[wave] = s; rss[wave] = ss; }
    __syncthreads();
    if (tid == 0) {
        float S = rs[0] + rs[1] + rs[2] + rs[3];
        float Q = rss[0] + rss[1] + rss[2] + rss[3];
        float mean = S / KVLR;
        float var = Q / KVLR - mean * mean;
        smean = mean; sinv = rsqrtf(var + EPSF);
    }
    __syncthreads();
    float mean = smean, inv = sinv;
    __bf16* kc = Kc + row * 576;
    kc[tid]       = (__bf16)((v0 - mean) * inv * kvw[tid]);
    kc[tid + 256] = (__bf16)((v1 - mean) * inv * kvw[tid + 256]);
    if (tid < 32) {
        float x1 = kr[KVLR + tid], x2 = kr[KVLR + 32 + tid];
        kc[512 + tid]      = (__bf16)(x1 * cr[tid] - x2 * sr[tid]);
        kc[512 + 32 + tid] = (__bf16)(x2 * cr[32 + tid] + x1 * sr[32 + tid]);
    }
    const int bb = (int)(row >> 10), sp = (int)(row & 1023);
    const __bf16* qr = q + row * (NHD * QKD);
#pragma unroll
    for (int j = 0; j < 2; ++j) {
        int idx = tid + j * 256;
        int h = idx >> 5, p = idx & 31;
        const __bf16* base = qr + h * QKD + NOPE;
        float x1 = (float)base[p], x2 = (float)base[32 + p];
        __bf16* qcb = Qc + ((size_t)(bb * NHD + h) * SS + sp) * 576 + 512;
        qcb[p]      = (__bf16)(x1 * cr[p] - x2 * sr[p]);
        qcb[32 + p] = (__bf16)(x2 * cr[32 + p] + x1 * sr[32 + p]);
    }
}

// ---------------------------------------------------------------------------
extern "C" void kernel_launch(void* const* d_in, const int* in_sizes, int n_in,
                              void* d_out, int out_size, void* d_ws, size_t ws_size,
                              hipStream_t stream)
{
    const float* hidden    = (const float*)d_in[0];
    const float* cosb      = (const float*)d_in[1];
    const float* sinb      = (const float*)d_in[2];
    const float* w_qa      = (const float*)d_in[3];
    const float* q_a_ln_w  = (const float*)d_in[4];
    const float* w_qb      = (const float*)d_in[5];
    const float* w_kva     = (const float*)d_in[6];
    const float* kv_a_ln_w = (const float*)d_in[7];
    const float* W_UK_T    = (const float*)d_in[8];
    const float* W_UV      = (const float*)d_in[9];
    const float* w_o       = (const float*)d_in[10];
    float* out = (float*)d_out;

    const int M = BB * SS;  // 2048
    // ---- HEAD region: transient buffers, later aliased by Sc (67.1 MB) ----
    float*  qakva = (float*)d_ws;
    __bf16* Xb    = (__bf16*)(qakva + (size_t)M * NCOMB);
    __bf16* qab   = Xb    + (size_t)M * HH;
    __bf16* qb    = qab   + (size_t)M * QLR;
    __bf16* qlatb = qb    + (size_t)M * NHD * QKD;   // slot kept (unused now)
    __bf16* Sc    = (__bf16*)d_ws;                    // aliases head after qlat
    // ---- TAIL region: persistent ----
    __bf16* Kc    = qlatb + (size_t)M * NHD * KVLR;   // M*576
    __bf16* Qc    = Kc    + (size_t)M * 576;          // M*9216
    __bf16* Vt    = Qc    + (size_t)M * NHD * 576;    // 2*512*1024
    __bf16* ctxb  = Vt    + (size_t)BB * 512 * SS;    // M*8192
    __bf16* ohb   = ctxb  + (size_t)M * NHD * KVLR;   // M*2048
    __bf16* w_cmb = ohb   + (size_t)M * HH;           // 2176*2048
    __bf16* w_qbb = w_cmb + (size_t)NCOMB * HH;       // 3072*1536
    __bf16* Wkb   = w_qbb + (size_t)NHD * QKD * QLR;  // 16*512*128
    __bf16* Wvb   = Wkb   + (size_t)NHD * KVLR * NOPE;// 16*128*512
    __bf16* w_ob  = Wvb   + (size_t)NHD * VDIM * KVLR;// 2048*2048

    dim3 blk(256);

    // --- casts ---
    castf2b<<<dim3((M * HH) / 1024), blk, 0, stream>>>(hidden, Xb, M * HH);
    cast_comb<<<dim3((NCOMB * HH) / 1024), blk, 0, stream>>>(w_qa, w_kva, w_cmb);
    castf2b<<<dim3((NHD * QKD * QLR) / 1024), blk, 0, stream>>>(w_qb, w_qbb, NHD * QKD * QLR);
    castf2b<<<dim3((HH * HH) / 1024), blk, 0, stream>>>(w_o, w_ob, HH * HH);
    transpose_cast<<<dim3(KVLR / 32, NOPE / 32, NHD), blk, 0, stream>>>(W_UK_T, Wkb, NOPE, KVLR);
    transpose_cast<<<dim3(VDIM / 32, KVLR / 32, NHD), blk, 0, stream>>>(W_UV, Wvb, KVLR, VDIM);

    // 1+4 fused: qakva = Xb @ [w_qa; w_kva]^T   (2048 x 2176 x 2048)
    gemm_mfma<false, 64, 2><<<dim3(NCOMB / 128, M / 128, 1), blk, 0, stream>>>(
        Xb, w_cmb, qakva, M, NCOMB, HH, HH, HH, NCOMB, 0, 0, 0);
    // 2. qab = bf16(LN(qakva[:, :1536]))
    ln_kernel<<<dim3(M), blk, 0, stream>>>(qakva, q_a_ln_w, qab, QLR, NCOMB);
    // 3. qb = qab @ w_qb^T (bf16)              (2048 x 3072 x 1536)
    gemm_mfma<true, 64, 2><<<dim3(NHD * QKD / 128, M / 128, 1), blk, 0, stream>>>(
        qab, w_qbb, qb, M, NHD * QKD, QLR, QLR, QLR, NHD * QKD, 0, 0, 0);
    // 5. Kc = [LN(kv_c), rope(k_pe)] bf16; roped q_pe -> Qc[...,512:576)
    prep_kernel<<<dim3(M), blk, 0, stream>>>(qakva + QLR, NCOMB, kv_a_ln_w,
                                             cosb, sinb, Kc, qb, Qc);
    // 5b. Vt = transpose(Kc[:, :512])
    transpose_kc<<<dim3(SS / 32, 512 / 32, BB), blk, 0, stream>>>(Kc, Vt);
    // 6. Qc[...,0:512) = q_nope[h] @ Wkb[h]^T  (16 x [2048 x 512 x 128])
    gemm_qlat<<<dim3(KVLR / 128, M / 128, NHD), blk, 0, stream>>>(qb, Wkb, Qc);
    // 8a. Sc = causal scores (Qc @ Kc^T)*scale  [bf16, head region now dead]
    gemm_scores<<<dim3(8, 8, 32), blk, 0, stream>>>(Qc, Kc, Sc);
    // 8b. row softmax in place
    softmax_kernel<<<dim3(SS / 4, 32), blk, 0, stream>>>(Sc);
    // 8c. ctx = P @ V (causal k-bound)
    gemm_pv<<<dim3(4, 8, 32), blk, 0, stream>>>(Sc, Vt, ctxb);
    // 9. ohb[h] = ctx[h] @ Wvb[h]^T            (16 x [2048 x 128 x 512])
    gemm_mfma<true, 32, 4><<<dim3(VDIM / 128, M / 128, NHD), blk, 0, stream>>>(
        ctxb, Wvb, ohb, M, VDIM, KVLR,
        NHD * KVLR, KVLR, NHD * VDIM,
        (long long)KVLR, (long long)VDIM * KVLR, (long long)VDIM);
    // 10. out = ohb @ w_o^T (fp32)             (2048 x 2048 x 2048)
    gemm_mfma<false, 64, 2><<<dim3(HH / 128, M / 128, 1), blk, 0, stream>>>(
        ohb, w_ob, out, M, HH, NHD * VDIM, NHD * VDIM, NHD * VDIM, HH, 0, 0, 0);
}

// Round 4
// 340.156 us; speedup vs baseline: 1.2937x; 1.1027x over previous
//
#include <hip/hip_runtime.h>
#include <hip/hip_bf16.h>
#include <math.h>

#define BB 2
#define SS 1024
#define HH 2048
#define NHD 16
#define NOPE 128
#define ROPED 64
#define VDIM 128
#define QKD 192
#define QLR 1536
#define KVLR 512
#define EPSF 1e-5f
#define NCOMB 2176   // QLR + 576 kv + 64 pad

typedef __bf16 bf16x8 __attribute__((ext_vector_type(8)));
typedef float  f32x4  __attribute__((ext_vector_type(4)));

__device__ __forceinline__ void gload_lds16(const __bf16* g, __bf16* l) {
    __builtin_amdgcn_global_load_lds(
        (const __attribute__((address_space(1))) void*)g,
        (__attribute__((address_space(3))) void*)l, 16, 0, 0);
}

// ---------------------------------------------------------------------------
// Shared index/swizzle math for the 128x128 tile cores.
//   XOR swizzle on 16B chunks (both-sides involution, verified R1/R2):
//   BK=64: chunk ^= row&7 ; BK=32: chunk ^= (row>>1)&3  (2-way = free).
// ---------------------------------------------------------------------------

// Double-buffered 2-barrier core (R1 schedule, proven): for dense big-K GEMMs.
template<int BK>
__device__ __forceinline__ void gemm_core_dbuf(
    const __bf16* __restrict__ Ab, const __bf16* __restrict__ Bb,
    int lda, int ldb, int m0, int n0, int K, __bf16* lds, f32x4 acc[4][4])
{
    constexpr int CH    = BK / 8;
    constexpr int LPT   = CH / 2;
    constexpr int BUFE  = 256 * BK;
    constexpr int BOFF  = 128 * BK;
    constexpr int RSTEP = 2048 / BK;
    const int tid = threadIdx.x;
    const int w = tid >> 6, lane = tid & 63, quad = lane >> 4, ln = lane & 15;
    const int wm = (w >> 1) * 64, wn = (w & 1) * 64;
    const int nt = K / BK;

    const int sr  = tid / CH;
    const int spc = tid % CH;
    const int sc  = (BK == 64) ? (spc ^ (sr & 7)) : (spc ^ ((sr >> 1) & 3));
    const __bf16* gA = Ab + (size_t)(m0 + sr) * lda + sc * 8;
    const __bf16* gB = Bb + (size_t)(n0 + sr) * ldb + sc * 8;

    const int swm = (BK == 64) ? ((wm + ln) & 7) : (((wm + ln) >> 1) & 3);
    const int swn = (BK == 64) ? ((wn + ln) & 7) : (((wn + ln) >> 1) & 3);

    auto stage = [&](int buf, int kk) {
        __bf16* la = lds + buf * BUFE + w * 512;
        __bf16* lb = la + BOFF;
        const __bf16* ga = gA + kk;
        const __bf16* gb = gB + kk;
#pragma unroll
        for (int i = 0; i < LPT; ++i) {
            gload_lds16(ga + (size_t)(i * RSTEP) * lda, la + i * 2048);
            gload_lds16(gb + (size_t)(i * RSTEP) * ldb, lb + i * 2048);
        }
    };
    auto wait_stage = [&]() {
        if constexpr (BK == 64) asm volatile("s_waitcnt vmcnt(8)" ::: "memory");
        else                    asm volatile("s_waitcnt vmcnt(4)" ::: "memory");
    };

    stage(0, 0);
    stage(1, BK);
    wait_stage();
    __builtin_amdgcn_s_barrier();
    __builtin_amdgcn_sched_barrier(0);

    for (int t = 0; t < nt; ++t) {
        const int cur = t & 1;
        const __bf16* bufA = lds + cur * BUFE;
        const __bf16* bufB = bufA + BOFF;
        bf16x8 af[BK / 32][4], bv[BK / 32][4];
#pragma unroll
        for (int ks = 0; ks < BK / 32; ++ks)
#pragma unroll
            for (int i = 0; i < 4; ++i) {
                af[ks][i] = *(const bf16x8*)
                    &bufA[(wm + ln) * BK + i * 16 * BK + (((ks * 4 + quad) ^ swm) << 3)];
                bv[ks][i] = *(const bf16x8*)
                    &bufB[(wn + ln) * BK + i * 16 * BK + (((ks * 4 + quad) ^ swn) << 3)];
            }
        __builtin_amdgcn_s_setprio(1);
#pragma unroll
        for (int ks = 0; ks < BK / 32; ++ks)
#pragma unroll
            for (int mi = 0; mi < 4; ++mi)
#pragma unroll
                for (int ni = 0; ni < 4; ++ni)
                    acc[mi][ni] = __builtin_amdgcn_mfma_f32_16x16x32_bf16(
                        af[ks][mi], bv[ks][ni], acc[mi][ni], 0, 0, 0);
        __builtin_amdgcn_s_setprio(0);
        if (t + 1 < nt) {
            __builtin_amdgcn_sched_barrier(0);
            asm volatile("" ::: "memory");
            __builtin_amdgcn_s_barrier();          // (a) reads of buf[cur] done
            asm volatile("" ::: "memory");
            if (t + 2 < nt) {
                stage(cur, (t + 2) * BK);
                wait_stage();
            } else {
                asm volatile("s_waitcnt vmcnt(0)" ::: "memory");
            }
            __builtin_amdgcn_s_barrier();          // (b) publish t+1
            __builtin_amdgcn_sched_barrier(0);
        }
    }
}

// ---------------------------------------------------------------------------
// Triple-buffered 1-barrier core (BK=32: 48 KB LDS -> 3 blocks/CU).
//   Race screen (R3): (a) stage at iter t targets the buffer holding tile
//   t-1; all waves' ds_reads of t-1 completed under lgkmcnt(0) before
//   barrier(t-1), stage issues after it. (b) counted vmcnt(4) retires this
//   wave's tile-t+1 loads before the barrier; post-barrier all slices
//   resident (vmcnt in-order, m135). (c) buffer re-staged 3 iters after
//   staging; prior loads retired 1-2 iters earlier; each wave rewrites only
//   its own w*512 slice. Barrier count wave-uniform. vmcnt(0) only in
//   epilogue.
// ---------------------------------------------------------------------------
template<int BK>
__device__ __forceinline__ void gemm_core_tri(
    const __bf16* __restrict__ Ab, const __bf16* __restrict__ Bb,
    int lda, int ldb, int m0, int n0, int K, __bf16* lds, f32x4 acc[4][4])
{
    constexpr int CH    = BK / 8;
    constexpr int LPT   = CH / 2;
    constexpr int BUFE  = 256 * BK;
    constexpr int BOFF  = 128 * BK;
    constexpr int RSTEP = 2048 / BK;
    const int tid = threadIdx.x;
    const int w = tid >> 6, lane = tid & 63, quad = lane >> 4, ln = lane & 15;
    const int wm = (w >> 1) * 64, wn = (w & 1) * 64;
    const int nt = K / BK;

    const int sr  = tid / CH;
    const int spc = tid % CH;
    const int sc  = (BK == 64) ? (spc ^ (sr & 7)) : (spc ^ ((sr >> 1) & 3));
    const __bf16* gA = Ab + (size_t)(m0 + sr) * lda + sc * 8;
    const __bf16* gB = Bb + (size_t)(n0 + sr) * ldb + sc * 8;

    const int swm = (BK == 64) ? ((wm + ln) & 7) : (((wm + ln) >> 1) & 3);
    const int swn = (BK == 64) ? ((wn + ln) & 7) : (((wn + ln) >> 1) & 3);

    auto stage = [&](__bf16* base, int kk) {
        __bf16* la = base + w * 512;
        __bf16* lb = la + BOFF;
        const __bf16* ga = gA + kk;
        const __bf16* gb = gB + kk;
#pragma unroll
        for (int i = 0; i < LPT; ++i) {
            gload_lds16(ga + (size_t)(i * RSTEP) * lda, la + i * 2048);
            gload_lds16(gb + (size_t)(i * RSTEP) * ldb, lb + i * 2048);
        }
    };

    __bf16* p0 = lds;               // tile t
    __bf16* p1 = lds + BUFE;        // tile t+1
    __bf16* p2 = lds + 2 * BUFE;    // stage target (tile t+2)

    stage(p0, 0);
    stage(p1, BK);
    if constexpr (BK == 64) asm volatile("s_waitcnt vmcnt(8)" ::: "memory");
    else                    asm volatile("s_waitcnt vmcnt(4)" ::: "memory");
    __builtin_amdgcn_s_barrier();
    __builtin_amdgcn_sched_barrier(0);

    for (int t = 0; t < nt; ++t) {
        bf16x8 af[BK / 32][4], bv[BK / 32][4];
#pragma unroll
        for (int ks = 0; ks < BK / 32; ++ks)
#pragma unroll
            for (int i = 0; i < 4; ++i) {
                af[ks][i] = *(const bf16x8*)
                    &p0[(wm + ln) * BK + i * 16 * BK + (((ks * 4 + quad) ^ swm) << 3)];
                bv[ks][i] = *(const bf16x8*)
                    &p0[BOFF + (wn + ln) * BK + i * 16 * BK + (((ks * 4 + quad) ^ swn) << 3)];
            }
        if (t + 2 < nt) stage(p2, (t + 2) * BK);   // overwrites tile t-1's buf
        asm volatile("s_waitcnt lgkmcnt(0)" ::: "memory");
        __builtin_amdgcn_sched_barrier(0);
        __builtin_amdgcn_s_setprio(1);
#pragma unroll
        for (int ks = 0; ks < BK / 32; ++ks)
#pragma unroll
            for (int mi = 0; mi < 4; ++mi)
#pragma unroll
                for (int ni = 0; ni < 4; ++ni)
                    acc[mi][ni] = __builtin_amdgcn_mfma_f32_16x16x32_bf16(
                        af[ks][mi], bv[ks][ni], acc[mi][ni], 0, 0, 0);
        __builtin_amdgcn_s_setprio(0);
        if (t + 1 < nt) {
            __builtin_amdgcn_sched_barrier(0);
            if (t + 2 < nt) {
                if constexpr (BK == 64) asm volatile("s_waitcnt vmcnt(8)" ::: "memory");
                else                    asm volatile("s_waitcnt vmcnt(4)" ::: "memory");
            } else {
                asm volatile("s_waitcnt vmcnt(0)" ::: "memory");
            }
            __builtin_amdgcn_s_barrier();          // single barrier per tile
            __builtin_amdgcn_sched_barrier(0);
        }
        __bf16* tmp = p0; p0 = p1; p1 = p2; p2 = tmp;
    }
}

// ---------------------------------------------------------------------------
// MFMA bf16 GEMM: C[M,N] = A[M,K] @ B[N,K]^T (batched via blockIdx.z)
// ---------------------------------------------------------------------------
template<bool OUT_BF16, int BK, int MINW, bool TRI>
__global__ __launch_bounds__(256, MINW) void gemm_mfma(
    const __bf16* __restrict__ A, const __bf16* __restrict__ B, void* __restrict__ Cv,
    int M, int N, int K, int lda, int ldb, int ldc,
    long long sA, long long sB, long long sC)
{
    __shared__ __bf16 lds[TRI ? 768 * BK : 512 * BK];
    const __bf16* Ab = A + (long long)blockIdx.z * sA;
    const __bf16* Bb = B + (long long)blockIdx.z * sB;
    const int tid = threadIdx.x;
    const int w = tid >> 6, lane = tid & 63, quad = lane >> 4, ln = lane & 15;
    const int m0 = blockIdx.y * 128, n0 = blockIdx.x * 128;
    const int wm = (w >> 1) * 64, wn = (w & 1) * 64;

    f32x4 acc[4][4];
#pragma unroll
    for (int i = 0; i < 4; ++i)
#pragma unroll
        for (int j = 0; j < 4; ++j) acc[i][j] = (f32x4){0.f, 0.f, 0.f, 0.f};

    if (TRI) gemm_core_tri<BK>(Ab, Bb, lda, ldb, m0, n0, K, lds, acc);
    else     gemm_core_dbuf<BK>(Ab, Bb, lda, ldb, m0, n0, K, lds, acc);

    if (OUT_BF16) {
        __bf16* Cb = (__bf16*)Cv + (long long)blockIdx.z * sC;
#pragma unroll
        for (int mi = 0; mi < 4; ++mi)
#pragma unroll
            for (int r = 0; r < 4; ++r) {
                size_t row = (size_t)(m0 + wm + mi * 16 + quad * 4 + r);
#pragma unroll
                for (int ni = 0; ni < 4; ++ni)
                    Cb[row * ldc + (n0 + wn + ni * 16 + ln)] = (__bf16)acc[mi][ni][r];
            }
    } else {
        float* Cb = (float*)Cv + (long long)blockIdx.z * sC;
#pragma unroll
        for (int mi = 0; mi < 4; ++mi)
#pragma unroll
            for (int r = 0; r < 4; ++r) {
                size_t row = (size_t)(m0 + wm + mi * 16 + quad * 4 + r);
#pragma unroll
                for (int ni = 0; ni < 4; ++ni)
                    Cb[row * ldc + (n0 + wn + ni * 16 + ln)] = acc[mi][ni][r];
            }
    }
}

// ---------------------------------------------------------------------------
// qlat GEMM with fused Qc scatter: Qc[b][h][s][0..512) = q_nope[h] @ Wk[h]^T
// ---------------------------------------------------------------------------
__global__ __launch_bounds__(256, 3) void gemm_qlat(
    const __bf16* __restrict__ qb, const __bf16* __restrict__ Wkb,
    __bf16* __restrict__ Qc)
{
    __shared__ __bf16 lds[768 * 32];
    const int h = blockIdx.z;
    const __bf16* Ab = qb + (size_t)h * QKD;
    const __bf16* Bb = Wkb + (size_t)h * KVLR * NOPE;
    const int tid = threadIdx.x;
    const int w = tid >> 6, lane = tid & 63, quad = lane >> 4, ln = lane & 15;
    const int m0 = blockIdx.y * 128, n0 = blockIdx.x * 128;
    const int wm = (w >> 1) * 64, wn = (w & 1) * 64;

    f32x4 acc[4][4];
#pragma unroll
    for (int i = 0; i < 4; ++i)
#pragma unroll
        for (int j = 0; j < 4; ++j) acc[i][j] = (f32x4){0.f, 0.f, 0.f, 0.f};

    gemm_core_tri<32>(Ab, Bb, NHD * QKD, NOPE, m0, n0, NOPE, lds, acc);

#pragma unroll
    for (int mi = 0; mi < 4; ++mi)
#pragma unroll
        for (int r = 0; r < 4; ++r) {
            int row = m0 + wm + mi * 16 + quad * 4 + r;   // b*S + s
            int bb = row >> 10, s = row & 1023;
            __bf16* dst = Qc + ((size_t)(bb * NHD + h) * SS + s) * 576;
#pragma unroll
            for (int ni = 0; ni < 4; ++ni)
                dst[n0 + wn + ni * 16 + ln] = (__bf16)acc[mi][ni][r];
        }
}

// ---------------------------------------------------------------------------
// Causal scores GEMM, exact-triangle grid + chunked XCD swizzle.
// grid = (36, 32): lin -> (z, lower-triangle tile). Each XCD gets 4
// consecutive z's (Q[z]+K[b] ~2.4MB, fits 4MB XCD L2).
// ---------------------------------------------------------------------------
__global__ __launch_bounds__(256, 3) void gemm_scores(
    const __bf16* __restrict__ Qc, const __bf16* __restrict__ Kc,
    __bf16* __restrict__ Sc)
{
    int lin = blockIdx.x + 36 * blockIdx.y;          // 0..1151
    lin = (lin & 7) * 144 + (lin >> 3);              // bijective chunk swizzle
    const int z = lin / 36;
    const int i = lin - z * 36;
    int mt = (int)((sqrtf(8.f * i + 1.f) - 1.f) * 0.5f);
    if (mt * (mt + 1) / 2 > i) --mt;
    if ((mt + 1) * (mt + 2) / 2 <= i) ++mt;
    const int nt = i - mt * (mt + 1) / 2;

    const int b = z >> 4;
    __shared__ __bf16 lds[768 * 32];
    const __bf16* Ab = Qc + (size_t)z * SS * 576;
    const __bf16* Bb = Kc + (size_t)b * SS * 576;
    __bf16* Cb = Sc + (size_t)z * SS * SS;
    const int tid = threadIdx.x;
    const int w = tid >> 6, lane = tid & 63, quad = lane >> 4, ln = lane & 15;
    const int m0 = mt * 128, n0 = nt * 128;
    const int wm = (w >> 1) * 64, wn = (w & 1) * 64;

    f32x4 acc[4][4];
#pragma unroll
    for (int i2 = 0; i2 < 4; ++i2)
#pragma unroll
        for (int j = 0; j < 4; ++j) acc[i2][j] = (f32x4){0.f, 0.f, 0.f, 0.f};

    gemm_core_tri<32>(Ab, Bb, 576, 576, m0, n0, 576, lds, acc);

    const float SCL2 = 0.07216878364870323f * 1.4426950408889634f;  // scale*log2e
#pragma unroll
    for (int mi = 0; mi < 4; ++mi)
#pragma unroll
        for (int r = 0; r < 4; ++r) {
            int row = m0 + wm + mi * 16 + quad * 4 + r;
#pragma unroll
            for (int ni = 0; ni < 4; ++ni) {
                int col = n0 + wn + ni * 16 + ln;
                float v = acc[mi][ni][r] * SCL2;
                if (col > row) v = -1e30f;
                Cb[(size_t)row * SS + col] = (__bf16)v;
            }
        }
}

// ---------------------------------------------------------------------------
// Row softmax (exp2 domain). One wave per row, shfl-only reductions.
// ---------------------------------------------------------------------------
__global__ __launch_bounds__(256) void softmax_kernel(__bf16* __restrict__ Sc)
{
    const int z = blockIdx.y;
    const int w = threadIdx.x >> 6, lane = threadIdx.x & 63;
    const int r = blockIdx.x * 4 + w;
    __bf16* row = Sc + (size_t)z * SS * SS + (size_t)r * SS;
    const int ncols = ((r >> 7) + 1) << 7;
    const int i0 = lane * 8, i1 = i0 + 512;
    const bool a0 = i0 < ncols, a1 = i1 < ncols;
    float v[16];
    float lmax = -1e30f;
    if (a0) {
        bf16x8 c = *(const bf16x8*)(row + i0);
#pragma unroll
        for (int j = 0; j < 8; ++j) { v[j] = (float)c[j]; lmax = fmaxf(lmax, v[j]); }
    }
    if (a1) {
        bf16x8 c = *(const bf16x8*)(row + i1);
#pragma unroll
        for (int j = 0; j < 8; ++j) { v[8 + j] = (float)c[j]; lmax = fmaxf(lmax, v[8 + j]); }
    }
#pragma unroll
    for (int off = 1; off < 64; off <<= 1) lmax = fmaxf(lmax, __shfl_xor(lmax, off));
    float lsum = 0.f;
    if (a0) {
#pragma unroll
        for (int j = 0; j < 8; ++j) { v[j] = __builtin_amdgcn_exp2f(v[j] - lmax); lsum += v[j]; }
    }
    if (a1) {
#pragma unroll
        for (int j = 0; j < 8; ++j) { v[8 + j] = __builtin_amdgcn_exp2f(v[8 + j] - lmax); lsum += v[8 + j]; }
    }
#pragma unroll
    for (int off = 1; off < 64; off <<= 1) lsum += __shfl_xor(lsum, off);
    const float inv = 1.f / lsum;
    if (a0) {
        bf16x8 c;
#pragma unroll
        for (int j = 0; j < 8; ++j) c[j] = (__bf16)(v[j] * inv);
        *(bf16x8*)(row + i0) = c;
    }
    if (a1) {
        bf16x8 c;
#pragma unroll
        for (int j = 0; j < 8; ++j) c[j] = (__bf16)(v[8 + j] * inv);
        *(bf16x8*)(row + i1) = c;
    }
}

// ---------------------------------------------------------------------------
// PV GEMM with chunked XCD swizzle: grid (32, 32) linear -> (z, mt, nt).
// Causal k-bound: K_eff = (mt+1)*128. Each XCD gets 4 consecutive z's.
// ---------------------------------------------------------------------------
__global__ __launch_bounds__(256, 3) void gemm_pv(
    const __bf16* __restrict__ Sc, const __bf16* __restrict__ Vt,
    __bf16* __restrict__ ctx)
{
    int lin = blockIdx.x + 32 * blockIdx.y;          // 0..1023
    lin = (lin & 7) * 128 + (lin >> 3);              // bijective chunk swizzle
    const int z = lin >> 5;
    const int rem = lin & 31;
    const int mt = rem >> 2, nt = rem & 3;

    const int b = z >> 4, h = z & 15;
    const int Keff = (mt + 1) * 128;
    __shared__ __bf16 lds[768 * 32];
    const __bf16* Ab = Sc + (size_t)z * SS * SS;
    const __bf16* Bb = Vt + (size_t)b * 512 * 1024;
    const int tid = threadIdx.x;
    const int w = tid >> 6, lane = tid & 63, quad = lane >> 4, ln = lane & 15;
    const int m0 = mt * 128, n0 = nt * 128;
    const int wm = (w >> 1) * 64, wn = (w & 1) * 64;

    f32x4 acc[4][4];
#pragma unroll
    for (int i = 0; i < 4; ++i)
#pragma unroll
        for (int j = 0; j < 4; ++j) acc[i][j] = (f32x4){0.f, 0.f, 0.f, 0.f};

    gemm_core_tri<32>(Ab, Bb, SS, 1024, m0, n0, Keff, lds, acc);

#pragma unroll
    for (int mi = 0; mi < 4; ++mi)
#pragma unroll
        for (int r = 0; r < 4; ++r) {
            int row = m0 + wm + mi * 16 + quad * 4 + r;
            __bf16* op = ctx + (size_t)(b * SS + row) * (NHD * KVLR) + h * KVLR;
#pragma unroll
            for (int ni = 0; ni < 4; ++ni)
                op[n0 + wn + ni * 16 + ln] = (__bf16)acc[mi][ni][r];
        }
}

// ---------------------------------------------------------------------------
// Cast helpers
// ---------------------------------------------------------------------------
__global__ __launch_bounds__(256) void castf2b(const float* __restrict__ in,
                                               __bf16* __restrict__ out, int n)
{
    int i = (blockIdx.x * 256 + threadIdx.x) * 4;
    if (i < n) {
        float4 v = *(const float4*)(in + i);
        out[i] = (__bf16)v.x; out[i + 1] = (__bf16)v.y;
        out[i + 2] = (__bf16)v.z; out[i + 3] = (__bf16)v.w;
    }
}

// combined [w_qa(1536); w_kva(576); pad(64)] x 2048 -> bf16
__global__ __launch_bounds__(256) void cast_comb(const float* __restrict__ wqa,
                                                 const float* __restrict__ wkva,
                                                 __bf16* __restrict__ out)
{
    int idx = (blockIdx.x * 256 + threadIdx.x) * 4;
    int row = idx >> 11, col = idx & 2047;
    const float* src;
    if (row < 1536)      src = wqa + (size_t)row * 2048 + col;
    else if (row < 2112) src = wkva + (size_t)(row - 1536) * 2048 + col;
    else {
        out[idx] = (__bf16)0.f; out[idx + 1] = (__bf16)0.f;
        out[idx + 2] = (__bf16)0.f; out[idx + 3] = (__bf16)0.f;
        return;
    }
    float4 v = *(const float4*)src;
    out[idx] = (__bf16)v.x; out[idx + 1] = (__bf16)v.y;
    out[idx + 2] = (__bf16)v.z; out[idx + 3] = (__bf16)v.w;
}

// batched transpose-cast: in[z][R][C] fp32 -> out[z][C][R] bf16
__global__ __launch_bounds__(256) void transpose_cast(const float* __restrict__ in,
                                                      __bf16* __restrict__ out,
                                                      int R, int C)
{
    __shared__ float t[32][33];
    in  += (size_t)blockIdx.z * R * C;
    out += (size_t)blockIdx.z * R * C;
    int c0 = blockIdx.x * 32, r0 = blockIdx.y * 32;
    int tx = threadIdx.x & 31, ty = threadIdx.x >> 5;
#pragma unroll
    for (int i = 0; i < 4; ++i) {
        int r = ty + i * 8;
        t[r][tx] = in[(size_t)(r0 + r) * C + c0 + tx];
    }
    __syncthreads();
#pragma unroll
    for (int i = 0; i < 4; ++i) {
        int rr = ty + i * 8;
        out[(size_t)(c0 + rr) * R + r0 + tx] = (__bf16)t[tx][rr];
    }
}

// Kc[b][k][f<512] bf16 -> Vt[b][f][k] bf16 (key-contiguous V)
__global__ __launch_bounds__(256) void transpose_kc(const __bf16* __restrict__ Kc,
                                                    __bf16* __restrict__ Vt)
{
    __shared__ __bf16 t[32][33];
    int b = blockIdx.z;
    int k0 = blockIdx.x * 32, f0 = blockIdx.y * 32;
    int tx = threadIdx.x & 31, ty = threadIdx.x >> 5;   // ty 0..7
    const __bf16* src = Kc + (size_t)b * SS * 576;
#pragma unroll
    for (int i = 0; i < 4; ++i)
        t[ty + i * 8][tx] = src[(size_t)(k0 + ty + i * 8) * 576 + f0 + tx];
    __syncthreads();
    __bf16* dst = Vt + (size_t)b * 512 * 1024;
#pragma unroll
    for (int i = 0; i < 4; ++i)
        dst[(size_t)(f0 + ty + i * 8) * 1024 + k0 + tx] = t[tx][ty + i * 8];
}

// ---------------------------------------------------------------------------
// LayerNorm fp32 in (row stride ldx) -> bf16 out (row stride N).
// ---------------------------------------------------------------------------
__global__ __launch_bounds__(256) void ln_kernel(const float* __restrict__ x,
                                                 const float* __restrict__ w,
                                                 __bf16* __restrict__ y, int N, int ldx)
{
    long long row = blockIdx.x;
    const float* xr = x + row * ldx;
    __bf16* yr = y + row * N;
    int tid = threadIdx.x;
    float s = 0.f, ss = 0.f;
    for (int i = tid; i < N; i += 256) { float v = xr[i]; s += v; ss += v * v; }
#pragma unroll
    for (int off = 32; off > 0; off >>= 1) { s += __shfl_down(s, off); ss += __shfl_down(ss, off); }
    __shared__ float rs[4], rss[4];
    __shared__ float smean, sinv;
    int wave = tid >> 6, lane = tid & 63;
    if (lane == 0) { rs[wave] = s; rss[wave] = ss; }
    __syncthreads();
    if (tid == 0) {
        float S = rs[0] + rs[1] + rs[2] + rs[3];
        float Q = rss[0] + rss[1] + rss[2] + rss[3];
        float mean = S / N;
        float var = Q / N - mean * mean;
        smean = mean; sinv = rsqrtf(var + EPSF);
    }
    __syncthreads();
    float mean = smean, inv = sinv;
    for (int i = tid; i < N; i += 256) yr[i] = (__bf16)((xr[i] - mean) * inv * w[i]);
}

// ---------------------------------------------------------------------------
// Per-token prep: Kc[row] = bf16(concat(LN(kva[:512])*w, rope(kva[512:576])))
// kva row stride ld; roped q_pe written straight into Qc cols [512,576).
// ---------------------------------------------------------------------------
__global__ __launch_bounds__(256) void prep_kernel(
    const float* __restrict__ kva, int ld, const float* __restrict__ kvw,
    const float* __restrict__ cosb, const float* __restrict__ sinb,
    __bf16* __restrict__ Kc, const __bf16* __restrict__ q,
    __bf16* __restrict__ Qc)
{
    long long row = blockIdx.x;
    const float* kr = kva + row * ld;
    const float* cr = cosb + row * ROPED;
    const float* sr = sinb + row * ROPED;
    int tid = threadIdx.x;
    float v0 = kr[tid], v1 = kr[tid + 256];
    float s = v0 + v1, ss = v0 * v0 + v1 * v1;
#pragma unroll
    for (int off = 32; off > 0; off >>= 1) { s += __shfl_down(s, off); ss += __shfl_down(ss, off); }
    __shared__ float rs[4], rss[4];
    __shared__ float smean, sinv;
    int wave = tid >> 6, lane = tid & 63;
    if (lane == 0) { rs[wave] = s; rss[wave] = ss; }
    __syncthreads();
    if (tid == 0) {
        float S = rs[0] + rs[1] + rs[2] + rs[3];
        float Q = rss[0] + rss[1] + rss[2] + rss[3];
        float mean = S / KVLR;
        float var = Q / KVLR - mean * mean;
        smean = mean; sinv = rsqrtf(var + EPSF);
    }
    __syncthreads();
    float mean = smean, inv = sinv;
    __bf16* kc = Kc + row * 576;
    kc[tid]       = (__bf16)((v0 - mean) * inv * kvw[tid]);
    kc[tid + 256] = (__bf16)((v1 - mean) * inv * kvw[tid + 256]);
    if (tid < 32) {
        float x1 = kr[KVLR + tid], x2 = kr[KVLR + 32 + tid];
        kc[512 + tid]      = (__bf16)(x1 * cr[tid] - x2 * sr[tid]);
        kc[512 + 32 + tid] = (__bf16)(x2 * cr[32 + tid] + x1 * sr[32 + tid]);
    }
    const int bb = (int)(row >> 10), sp = (int)(row & 1023);
    const __bf16* qr = q + row * (NHD * QKD);
#pragma unroll
    for (int j = 0; j < 2; ++j) {
        int idx = tid + j * 256;
        int h = idx >> 5, p = idx & 31;
        const __bf16* base = qr + h * QKD + NOPE;
        float x1 = (float)base[p], x2 = (float)base[32 + p];
        __bf16* qcb = Qc + ((size_t)(bb * NHD + h) * SS + sp) * 576 + 512;
        qcb[p]      = (__bf16)(x1 * cr[p] - x2 * sr[p]);
        qcb[32 + p] = (__bf16)(x2 * cr[32 + p] + x1 * sr[32 + p]);
    }
}

// ---------------------------------------------------------------------------
extern "C" void kernel_launch(void* const* d_in, const int* in_sizes, int n_in,
                              void* d_out, int out_size, void* d_ws, size_t ws_size,
                              hipStream_t stream)
{
    const float* hidden    = (const float*)d_in[0];
    const float* cosb      = (const float*)d_in[1];
    const float* sinb      = (const float*)d_in[2];
    const float* w_qa      = (const float*)d_in[3];
    const float* q_a_ln_w  = (const float*)d_in[4];
    const float* w_qb      = (const float*)d_in[5];
    const float* w_kva     = (const float*)d_in[6];
    const float* kv_a_ln_w = (const float*)d_in[7];
    const float* W_UK_T    = (const float*)d_in[8];
    const float* W_UV      = (const float*)d_in[9];
    const float* w_o       = (const float*)d_in[10];
    float* out = (float*)d_out;

    const int M = BB * SS;  // 2048
    // ---- HEAD region: transient buffers, later aliased by Sc (67.1 MB) ----
    float*  qakva = (float*)d_ws;
    __bf16* Xb    = (__bf16*)(qakva + (size_t)M * NCOMB);
    __bf16* qab   = Xb    + (size_t)M * HH;
    __bf16* qb    = qab   + (size_t)M * QLR;
    __bf16* qlatb = qb    + (size_t)M * NHD * QKD;   // slot kept (unused now)
    __bf16* Sc    = (__bf16*)d_ws;                    // aliases head after qlat
    // ---- TAIL region: persistent ----
    __bf16* Kc    = qlatb + (size_t)M * NHD * KVLR;   // M*576
    __bf16* Qc    = Kc    + (size_t)M * 576;          // M*9216
    __bf16* Vt    = Qc    + (size_t)M * NHD * 576;    // 2*512*1024
    __bf16* ctxb  = Vt    + (size_t)BB * 512 * SS;    // M*8192
    __bf16* ohb   = ctxb  + (size_t)M * NHD * KVLR;   // M*2048
    __bf16* w_cmb = ohb   + (size_t)M * HH;           // 2176*2048
    __bf16* w_qbb = w_cmb + (size_t)NCOMB * HH;       // 3072*1536
    __bf16* Wkb   = w_qbb + (size_t)NHD * QKD * QLR;  // 16*512*128
    __bf16* Wvb   = Wkb   + (size_t)NHD * KVLR * NOPE;// 16*128*512
    __bf16* w_ob  = Wvb   + (size_t)NHD * VDIM * KVLR;// 2048*2048

    dim3 blk(256);

    // --- casts ---
    castf2b<<<dim3((M * HH) / 1024), blk, 0, stream>>>(hidden, Xb, M * HH);
    cast_comb<<<dim3((NCOMB * HH) / 1024), blk, 0, stream>>>(w_qa, w_kva, w_cmb);
    castf2b<<<dim3((NHD * QKD * QLR) / 1024), blk, 0, stream>>>(w_qb, w_qbb, NHD * QKD * QLR);
    castf2b<<<dim3((HH * HH) / 1024), blk, 0, stream>>>(w_o, w_ob, HH * HH);
    transpose_cast<<<dim3(KVLR / 32, NOPE / 32, NHD), blk, 0, stream>>>(W_UK_T, Wkb, NOPE, KVLR);
    transpose_cast<<<dim3(VDIM / 32, KVLR / 32, NHD), blk, 0, stream>>>(W_UV, Wvb, KVLR, VDIM);

    // 1+4 fused: qakva = Xb @ [w_qa; w_kva]^T   (2048 x 2176 x 2048)
    gemm_mfma<false, 64, 2, false><<<dim3(NCOMB / 128, M / 128, 1), blk, 0, stream>>>(
        Xb, w_cmb, qakva, M, NCOMB, HH, HH, HH, NCOMB, 0, 0, 0);
    // 2. qab = bf16(LN(qakva[:, :1536]))
    ln_kernel<<<dim3(M), blk, 0, stream>>>(qakva, q_a_ln_w, qab, QLR, NCOMB);
    // 3. qb = qab @ w_qb^T (bf16)              (2048 x 3072 x 1536)
    gemm_mfma<true, 64, 2, false><<<dim3(NHD * QKD / 128, M / 128, 1), blk, 0, stream>>>(
        qab, w_qbb, qb, M, NHD * QKD, QLR, QLR, QLR, NHD * QKD, 0, 0, 0);
    // 5. Kc = [LN(kv_c), rope(k_pe)] bf16; roped q_pe -> Qc[...,512:576)
    prep_kernel<<<dim3(M), blk, 0, stream>>>(qakva + QLR, NCOMB, kv_a_ln_w,
                                             cosb, sinb, Kc, qb, Qc);
    // 5b. Vt = transpose(Kc[:, :512])
    transpose_kc<<<dim3(SS / 32, 512 / 32, BB), blk, 0, stream>>>(Kc, Vt);
    // 6. Qc[...,0:512) = q_nope[h] @ Wkb[h]^T  (16 x [2048 x 512 x 128])
    gemm_qlat<<<dim3(KVLR / 128, M / 128, NHD), blk, 0, stream>>>(qb, Wkb, Qc);
    // 8a. Sc = causal scores, exact triangle grid (1152 blocks)
    gemm_scores<<<dim3(36, 32), blk, 0, stream>>>(Qc, Kc, Sc);
    // 8b. row softmax in place
    softmax_kernel<<<dim3(SS / 4, 32), blk, 0, stream>>>(Sc);
    // 8c. ctx = P @ V (causal k-bound), linear grid + swizzle
    gemm_pv<<<dim3(32, 32), blk, 0, stream>>>(Sc, Vt, ctxb);
    // 9. ohb[h] = ctx[h] @ Wvb[h]^T            (16 x [2048 x 128 x 512])
    gemm_mfma<true, 32, 3, true><<<dim3(VDIM / 128, M / 128, NHD), blk, 0, stream>>>(
        ctxb, Wvb, ohb, M, VDIM, KVLR,
        NHD * KVLR, KVLR, NHD * VDIM,
        (long long)KVLR, (long long)VDIM * KVLR, (long long)VDIM);
    // 10. out = ohb @ w_o^T (fp32)             (2048 x 2048 x 2048)
    gemm_mfma<false, 64, 2, false><<<dim3(HH / 128, M / 128, 1), blk, 0, stream>>>(
        ohb, w_ob, out, M, HH, NHD * VDIM, NHD * VDIM, NHD * VDIM, HH, 0, 0, 0);
}